// Round 12
// baseline (149.223 us; speedup 1.0000x reference)
//
#include <hip/hip_runtime.h>

// FlexAttention (sliding-window causal + per-head sink), R12.
// B=2,H=16,S=2048,D=64,W=1024.
//
// R12 breaks the R6-R11 register wall (3 waves/SIMD @ ~150 unified regs):
//  - Prologue converts K -> bf16 [bh][key][dim], V -> bf16 TRANSPOSED
//    [bh][dim][key] into d_ws (once; tiles are re-staged ~3.4x by the
//    schedule, so this also deduplicates fp32->bf16 conversion).
//  - Main stages K/V via __builtin_amdgcn_global_load_lds width=16 (async
//    DMA, no VGPR transit): 4 insts/wave/tile replace 8 loads + 12 LDS
//    writes + ~30 cvt/pack. Per-lane SOURCE addresses are permuted
//    (row=g>>3, gran=(g&7)^((row>>1)&7), still 128B-coalesced) so the
//    DMA's linear lane->LDS placement EQUALS the swizzled layout; all
//    fragment reads identical to R9 (conflict-free).
//  - kreg/vreg gone (-32 regs) -> live ~100 -> __launch_bounds__(256,4)
//    fits WITHOUT R7's spill -> 4 blocks/CU. 36-bin x 6-tile schedule.
//  - exp2-domain softmax (Q pre-scaled by scale*log2e; sink logit too;
//    combine uses exp2f). Eager online softmax (R9 form), tree reductions.
// Layouts (m74/m101): A[m=l&31][k=(l>>5)*8+j], B[k=..][n=l&31],
// C/D[row=(rg&3)+8*(rg>>2)+4*(l>>5)][col=l&31].
// Workspace: Kbf 8.4MB + Vt 8.4MB + O partials 25.2MB + ml 1.6MB = 43.5MB.

typedef __bf16 bf16x8 __attribute__((ext_vector_type(8)));
typedef __bf16 bf16x4 __attribute__((ext_vector_type(4)));
typedef float  f32x16 __attribute__((ext_vector_type(16)));

#define NT 256
#define NEG_BIG (-3.0e38f)
#define LOG2E 1.44269504089f

__device__ __forceinline__ int swz(int row, int gran) {
    return row * 64 + ((gran ^ ((row >> 1) & 7)) << 3);
}

__device__ __forceinline__ bf16x4 xswap32(bf16x4 v) {
    union { bf16x4 v; int i[2]; } u;
    u.v = v;
    u.i[0] = __shfl_xor(u.i[0], 32, 64);
    u.i[1] = __shfl_xor(u.i[1], 32, 64);
    return u.v;
}

#define GLDS(gp, lp) __builtin_amdgcn_global_load_lds( \
    (const __attribute__((address_space(1))) unsigned int*)(gp), \
    (__attribute__((address_space(3))) unsigned int*)(lp), 16, 0, 0)

// ---- baked schedule: 36 bins/bh x 6 tiles (R7/R10 tables, verified) ----
__device__ const int SEG_N[36]     = {2,1,1,2,1,1,1,1,1,2,1,1, 1,1,1,1,1,1,1,1,1,1,1,1,1,1,1,1,1,1,1,1,1,1,1,1};
__device__ const int SEG_IT[36][2] = {
  {0,1},{2,0},{3,0},{3,4},{4,0},{5,0},{5,0},{6,0},{6,0},{6,7},{7,0},{7,0},
  {8,0},{8,0},{8,0},{9,0},{9,0},{9,0},{10,0},{10,0},{10,0},{11,0},{11,0},{11,0},
  {12,0},{12,0},{12,0},{13,0},{13,0},{13,0},{14,0},{14,0},{14,0},{15,0},{15,0},{15,0}};
__device__ const int SEG_J0[36][2] = {
  {0,0},{0,0},{0,0},{6,0},{4,0},{0,0},{6,0},{0,0},{6,0},{12,0},{4,0},{10,0},
  {0,0},{6,0},{12,0},{0,0},{6,0},{12,0},{0,0},{6,0},{12,0},{0,0},{6,0},{12,0},
  {0,0},{6,0},{12,0},{0,0},{6,0},{12,0},{0,0},{6,0},{12,0},{0,0},{6,0},{12,0}};
__device__ const int SEG_J1[36][2] = {
  {2,4},{6,0},{6,0},{8,4},{10,0},{6,0},{12,0},{6,0},{12,0},{14,4},{10,0},{16,0},
  {6,0},{12,0},{18,0},{6,0},{12,0},{18,0},{6,0},{12,0},{18,0},{6,0},{12,0},{18,0},
  {6,0},{12,0},{18,0},{6,0},{12,0},{18,0},{6,0},{12,0},{18,0},{6,0},{12,0},{18,0}};
__device__ const int SEG_SX[36][2] = {
  {0,0},{0,0},{0,0},{1,0},{1,0},{0,0},{1,0},{0,0},{1,0},{2,0},{1,0},{2,0},
  {0,0},{1,0},{2,0},{0,0},{1,0},{2,0},{0,0},{1,0},{2,0},{0,0},{1,0},{2,0},
  {0,0},{1,0},{2,0},{0,0},{1,0},{2,0},{0,0},{1,0},{2,0},{0,0},{1,0},{2,0}};
__device__ const int NSEG_ITEM[16] = {1,1,1,2,2,2,3,3, 3,3,3,3,3,3,3,3};

// ================= prologue: K,V fp32 -> bf16 (V transposed) =================
__global__ __launch_bounds__(256) void flex_r12_pre(
    const float* __restrict__ K, const float* __restrict__ V,
    void* __restrict__ WS, const int S)
{
    const int t    = threadIdx.x;
    const int nkt  = S >> 6;                       // 32 key-tiles per bh
    const int NBH  = gridDim.x / nkt;
    const int bh   = blockIdx.x / nkt;
    const int kt   = blockIdx.x - bh * nkt;
    const size_t basebh = (size_t)bh * S * 64;

    __bf16* Kb = (__bf16*)WS + basebh;                              // [key][dim]
    __bf16* Vt = (__bf16*)WS + (size_t)NBH * S * 64 + basebh;       // [dim][key]

    const float4* kp4 = (const float4*)(K + basebh + (size_t)kt * 64 * 64);
    const float4* vp4 = (const float4*)(V + basebh + (size_t)kt * 64 * 64);

    // K: straight convert, [key][dim]
    #pragma unroll
    for (int i = 0; i < 4; ++i) {
        const int f = i * 256 + t;
        const int key = f >> 4, d4 = f & 15;
        float4 x = kp4[f];
        bf16x4 b = { (__bf16)x.x, (__bf16)x.y, (__bf16)x.z, (__bf16)x.w };
        *(bf16x4*)&Kb[(size_t)(kt * 64 + key) * 64 + d4 * 4] = b;
    }
    // V: 4x4 register transpose -> [dim][key]
    const int dgi = t & 15, kgi = t >> 4;
    float4 a0 = vp4[(4 * kgi + 0) * 16 + dgi];
    float4 a1 = vp4[(4 * kgi + 1) * 16 + dgi];
    float4 a2 = vp4[(4 * kgi + 2) * 16 + dgi];
    float4 a3 = vp4[(4 * kgi + 3) * 16 + dgi];
    bf16x4 w0 = { (__bf16)a0.x, (__bf16)a1.x, (__bf16)a2.x, (__bf16)a3.x };
    bf16x4 w1 = { (__bf16)a0.y, (__bf16)a1.y, (__bf16)a2.y, (__bf16)a3.y };
    bf16x4 w2 = { (__bf16)a0.z, (__bf16)a1.z, (__bf16)a2.z, (__bf16)a3.z };
    bf16x4 w3 = { (__bf16)a0.w, (__bf16)a1.w, (__bf16)a2.w, (__bf16)a3.w };
    const int kb0 = kt * 64 + 4 * kgi;
    *(bf16x4*)&Vt[(size_t)(4 * dgi + 0) * S + kb0] = w0;
    *(bf16x4*)&Vt[(size_t)(4 * dgi + 1) * S + kb0] = w1;
    *(bf16x4*)&Vt[(size_t)(4 * dgi + 2) * S + kb0] = w2;
    *(bf16x4*)&Vt[(size_t)(4 * dgi + 3) * S + kb0] = w3;
}

// ================================ main ================================
__global__ __launch_bounds__(NT, 4) void flex_r12_main(
    const float* __restrict__ Q, const float* __restrict__ SINKW,
    const int* __restrict__ SWIN, void* __restrict__ WS,
    float* __restrict__ OUT, const int H, const int S)
{
    const int t    = threadIdx.x;
    const int lane = t & 63;
    const int w    = t >> 6;
    const int c    = lane & 31;
    const int hl   = lane >> 5;
    const int W    = SWIN[0];
    const float qscale = 0.125f * LOG2E;   // exp2 domain

    const int NBH = gridDim.x / 36;
    const int bh  = blockIdx.x / 36;
    const int b36 = blockIdx.x - bh * 36;
    const int h   = bh % H;
    const float sw = SINKW[h] * LOG2E;     // sink logit in log2 domain

    __shared__ __align__(16) __bf16 k_lds[2][64 * 64];
    __shared__ __align__(16) __bf16 v_lds[2][64 * 64];

    const size_t basebh = (size_t)bh * S * 64;
    const char* KbB = (const char*)WS + basebh * 2;                          // [key][dim] bf16
    const char* VtB = (const char*)WS + (size_t)NBH * S * 128 + basebh * 2;  // [dim][key] bf16
    __bf16* O_ws  = (__bf16*)WS + (size_t)2 * NBH * S * 64;
    float2* ml_ws = (float2*)((char*)WS + (size_t)4 * NBH * S * 64
                                        + (size_t)NBH * 48 * 16384);

    // ---- per-lane DMA source offsets (loop-invariant) ----
    // LDS granule g = chunk*64 + lane holds source (row=g>>3, gran=(g&7)^((row>>1)&7))
    int koff[2], voff[2];
    #pragma unroll
    for (int i = 0; i < 2; ++i) {
        const int qc  = 2 * w + i;
        const int row = qc * 8 + (lane >> 3);
        const int gr  = (lane & 7) ^ ((row >> 1) & 7);
        koff[i] = row * 128 + gr * 16;          // K tile: row stride 128B
        voff[i] = row * (S * 2) + gr * 16;      // V: row=dim, stride S*2B
    }

    auto dma = [&](int kt, int buf) {
        const char* ks = KbB + (size_t)kt * 8192;   // 64 rows x 128B
        const char* vs = VtB + (size_t)kt * 128;    // 64-key column offset
        #pragma unroll
        for (int i = 0; i < 2; ++i) {
            GLDS(ks + koff[i], (char*)&k_lds[buf][0] + (2 * w + i) * 1024);
            GLDS(vs + voff[i], (char*)&v_lds[buf][0] + (2 * w + i) * 1024);
        }
    };

    const int ns = SEG_N[b36];
    // first tile DMA into buffer 0 (drained by the first in-loop barrier)
    {
        const int it0 = SEG_IT[b36][0];
        const int ktA0 = (2 * it0 - 16 > 0) ? (2 * it0 - 16) : 0;
        dma(ktA0 + SEG_J0[b36][0], 0);
    }

    int par = 0;

    for (int s = 0; s < ns; ++s) {
        const int item = SEG_IT[b36][s];
        const int j0   = SEG_J0[b36][s];
        const int j1   = SEG_J1[b36][s];
        const int sidx = SEG_SX[b36][s];
        const int ktA  = (2 * item - 16 > 0) ? (2 * item - 16) : 0;
        const int qw0  = item * 128 + 32 * w;
        const int qi   = qw0 + c;

        // ---- Q B-fragments (pre-scaled into exp2 domain) ----
        bf16x8 bq[4];
        {
            const float4* qp4 = (const float4*)(Q + basebh + (size_t)qi * 64);
            #pragma unroll
            for (int ks = 0; ks < 4; ++ks) {
                float4 f0 = qp4[4 * ks + 2 * hl];
                float4 f1 = qp4[4 * ks + 2 * hl + 1];
                bq[ks][0] = (__bf16)(f0.x * qscale); bq[ks][1] = (__bf16)(f0.y * qscale);
                bq[ks][2] = (__bf16)(f0.z * qscale); bq[ks][3] = (__bf16)(f0.w * qscale);
                bq[ks][4] = (__bf16)(f1.x * qscale); bq[ks][5] = (__bf16)(f1.y * qscale);
                bq[ks][6] = (__bf16)(f1.z * qscale); bq[ks][7] = (__bf16)(f1.w * qscale);
            }
        }

        float mrun = (sidx == 0) ? sw : NEG_BIG;
        float lrun = (sidx == 0) ? 1.0f : 0.0f;
        f32x16 accO0, accO1;
        #pragma unroll
        for (int i = 0; i < 16; ++i) { accO0[i] = 0.0f; accO1[i] = 0.0f; }

        for (int j = j0; j < j1; ++j) {
            const int k0 = (ktA + j) * 64;

            __syncthreads();   // buf[par] DMA drained & visible; prev compute done

            // ---- issue DMA for next tile into the other buffer (async) ----
            int nkt = -1;
            if (j + 1 < j1) nkt = ktA + j + 1;
            else if (s + 1 < ns) {
                const int it2 = SEG_IT[b36][s + 1];
                const int ktA2 = (2 * it2 - 16 > 0) ? (2 * it2 - 16) : 0;
                nkt = ktA2 + SEG_J0[b36][s + 1];
            }
            if (nkt >= 0) dma(nkt, par ^ 1);

            // ---- S^T = K · Q^T ----
            const __bf16* kb = k_lds[par];
            const __bf16* vb = v_lds[par];
            f32x16 accS0, accS1;
            #pragma unroll
            for (int i = 0; i < 16; ++i) { accS0[i] = 0.0f; accS1[i] = 0.0f; }
            #pragma unroll
            for (int ks = 0; ks < 4; ++ks) {
                bf16x8 ka0 = *(const bf16x8*)&kb[swz(c,      2 * ks + hl)];
                bf16x8 ka1 = *(const bf16x8*)&kb[swz(32 + c, 2 * ks + hl)];
                accS0 = __builtin_amdgcn_mfma_f32_32x32x16_bf16(ka0, bq[ks], accS0, 0, 0, 0);
                accS1 = __builtin_amdgcn_mfma_f32_32x32x16_bf16(ka1, bq[ks], accS1, 0, 0, 0);
            }

            // ---- mask (wave-uniform skip when interior) ----
            const bool interior = (k0 + 63 <= qw0) && (qw0 + 31 - k0 <= W);
            if (!interior) {
                #pragma unroll
                for (int rg = 0; rg < 16; ++rg) {
                    const int kb2 = (rg & 3) + 8 * (rg >> 2) + 4 * hl;
                    const int ki0 = k0 + kb2, ki1 = k0 + 32 + kb2;
                    if (!((ki0 <= qi) && (qi - ki0 <= W))) accS0[rg] = -1e30f;
                    if (!((ki1 <= qi) && (qi - ki1 <= W))) accS1[rg] = -1e30f;
                }
            }

            // ---- online softmax (eager, exp2 domain, tree reductions) ----
            float mm[8];
            #pragma unroll
            for (int i = 0; i < 8; ++i)
                mm[i] = fmaxf(fmaxf(accS0[2*i], accS0[2*i+1]),
                              fmaxf(accS1[2*i], accS1[2*i+1]));
            float mx = fmaxf(fmaxf(fmaxf(mm[0], mm[1]), fmaxf(mm[2], mm[3])),
                             fmaxf(fmaxf(mm[4], mm[5]), fmaxf(mm[6], mm[7])));
            mx = fmaxf(mx, __shfl_xor(mx, 32, 64));
            const float mnew  = fmaxf(mrun, mx);
            const float alpha = exp2f(mrun - mnew);
            #pragma unroll
            for (int i = 0; i < 16; ++i) accS0[i] = exp2f(accS0[i] - mnew);
            #pragma unroll
            for (int i = 0; i < 16; ++i) accS1[i] = exp2f(accS1[i] - mnew);
            float pp[8];
            #pragma unroll
            for (int i = 0; i < 8; ++i)
                pp[i] = (accS0[2*i] + accS0[2*i+1]) + (accS1[2*i] + accS1[2*i+1]);
            float ps = ((pp[0] + pp[1]) + (pp[2] + pp[3]))
                     + ((pp[4] + pp[5]) + (pp[6] + pp[7]));
            ps += __shfl_xor(ps, 32, 64);
            lrun = lrun * alpha + ps;
            mrun = mnew;
            #pragma unroll
            for (int i = 0; i < 16; ++i) { accO0[i] *= alpha; accO1[i] *= alpha; }

            // ---- P -> B-fragments IN REGISTERS (half-wave quad exchange) ----
            bf16x4 qA = { (__bf16)accS0[0],  (__bf16)accS0[1],  (__bf16)accS0[2],  (__bf16)accS0[3]  };
            bf16x4 qB = { (__bf16)accS0[4],  (__bf16)accS0[5],  (__bf16)accS0[6],  (__bf16)accS0[7]  };
            bf16x4 qC = { (__bf16)accS0[8],  (__bf16)accS0[9],  (__bf16)accS0[10], (__bf16)accS0[11] };
            bf16x4 qD = { (__bf16)accS0[12], (__bf16)accS0[13], (__bf16)accS0[14], (__bf16)accS0[15] };
            bf16x4 qE = { (__bf16)accS1[0],  (__bf16)accS1[1],  (__bf16)accS1[2],  (__bf16)accS1[3]  };
            bf16x4 qF = { (__bf16)accS1[4],  (__bf16)accS1[5],  (__bf16)accS1[6],  (__bf16)accS1[7]  };
            bf16x4 qG = { (__bf16)accS1[8],  (__bf16)accS1[9],  (__bf16)accS1[10], (__bf16)accS1[11] };
            bf16x4 qH = { (__bf16)accS1[12], (__bf16)accS1[13], (__bf16)accS1[14], (__bf16)accS1[15] };
            bf16x4 r0 = xswap32(hl ? qA : qB);
            bf16x4 r1 = xswap32(hl ? qC : qD);
            bf16x4 r2 = xswap32(hl ? qE : qF);
            bf16x4 r3 = xswap32(hl ? qG : qH);
            bf16x4 lo0 = hl ? r0 : qA, hi0 = hl ? qB : r0;
            bf16x4 lo1 = hl ? r1 : qC, hi1 = hl ? qD : r1;
            bf16x4 lo2 = hl ? r2 : qE, hi2 = hl ? qF : r2;
            bf16x4 lo3 = hl ? r3 : qG, hi3 = hl ? qH : r3;
            bf16x8 bp[4];
            #pragma unroll
            for (int e = 0; e < 4; ++e) {
                bp[0][e] = lo0[e]; bp[0][4+e] = hi0[e];
                bp[1][e] = lo1[e]; bp[1][4+e] = hi1[e];
                bp[2][e] = lo2[e]; bp[2][4+e] = hi2[e];
                bp[3][e] = lo3[e]; bp[3][4+e] = hi3[e];
            }

            // ---- O^T += V^T · P^T ----
            #pragma unroll
            for (int ks = 0; ks < 4; ++ks) {
                bf16x8 va0 = *(const bf16x8*)&vb[swz(c,      2 * ks + hl)];
                bf16x8 va1 = *(const bf16x8*)&vb[swz(32 + c, 2 * ks + hl)];
                accO0 = __builtin_amdgcn_mfma_f32_32x32x16_bf16(va0, bp[ks], accO0, 0, 0, 0);
                accO1 = __builtin_amdgcn_mfma_f32_32x32x16_bf16(va1, bp[ks], accO1, 0, 0, 0);
            }

            par ^= 1;
        }

        if (item < 3) {
            // ---- single-segment item: write normalized output directly ----
            const float inv = 1.0f / lrun;
            float* ob = OUT + basebh + (size_t)qi * 64;
            #pragma unroll
            for (int rg = 0; rg < 4; ++rg) {
                float4 f0 = { accO0[4*rg+0]*inv, accO0[4*rg+1]*inv,
                              accO0[4*rg+2]*inv, accO0[4*rg+3]*inv };
                float4 f1 = { accO1[4*rg+0]*inv, accO1[4*rg+1]*inv,
                              accO1[4*rg+2]*inv, accO1[4*rg+3]*inv };
                *(float4*)&ob[     8 * rg + 4 * hl] = f0;
                *(float4*)&ob[32 + 8 * rg + 4 * hl] = f1;
            }
        } else {
            // ---- write partials (m in log2 domain; combine uses exp2) ----
            const int slot = (bh * 16 + item) * 3 + sidx;
            const int qrel = 32 * w + c;
            if (hl == 0) ml_ws[(size_t)slot * 128 + qrel] = make_float2(mrun, lrun);
            __bf16* Os = O_ws + (size_t)slot * 8192 + (size_t)qrel * 64;
            #pragma unroll
            for (int qd = 0; qd < 4; ++qd) {
                const int d0 = 8 * qd + 4 * hl;
                bf16x4 b0 = { (__bf16)accO0[4*qd+0], (__bf16)accO0[4*qd+1],
                              (__bf16)accO0[4*qd+2], (__bf16)accO0[4*qd+3] };
                bf16x4 b1 = { (__bf16)accO1[4*qd+0], (__bf16)accO1[4*qd+1],
                              (__bf16)accO1[4*qd+2], (__bf16)accO1[4*qd+3] };
                *(bf16x4*)&Os[d0]      = b0;
                *(bf16x4*)&Os[32 + d0] = b1;
            }
        }
    }
}

// =============================== combine ===============================
__global__ __launch_bounds__(256) void flex_r12_combine(
    const void* __restrict__ WS, float* __restrict__ OUT, const int H, const int S)
{
    const int NBH  = gridDim.x / 13;
    const int bi   = blockIdx.x;
    const int bh   = bi / 13;
    const int item = 3 + (bi - bh * 13);      // items 3..15
    const int ns   = NSEG_ITEM[item];
    const int t    = threadIdx.x;
    const int q    = t >> 1;
    const int half = t & 1;

    const __bf16* O_ws = (const __bf16*)WS + (size_t)2 * NBH * S * 64;
    const float2* ml_ws = (const float2*)((const char*)WS + (size_t)4 * NBH * S * 64
                                          + (size_t)NBH * 48 * 16384);
    const int base = (bh * 16 + item) * 3;

    float m[3], lv[3], a[3];
    float mst = NEG_BIG;
    for (int s = 0; s < ns; ++s) {
        float2 e = ml_ws[(size_t)(base + s) * 128 + q];
        m[s] = e.x; lv[s] = e.y;
        mst = fmaxf(mst, m[s]);
    }
    float lst = 0.0f;
    for (int s = 0; s < ns; ++s) { a[s] = exp2f(m[s] - mst); lst += a[s] * lv[s]; }
    const float inv = 1.0f / lst;

    float acc[32];
    #pragma unroll
    for (int i = 0; i < 32; ++i) acc[i] = 0.0f;
    for (int s = 0; s < ns; ++s) {
        const __bf16* Os = O_ws + (size_t)(base + s) * 8192 + (size_t)q * 64 + 32 * half;
        const float as = a[s];
        #pragma unroll
        for (int v8 = 0; v8 < 4; ++v8) {
            bf16x8 o = *(const bf16x8*)&Os[8 * v8];
            #pragma unroll
            for (int jj = 0; jj < 8; ++jj) acc[8 * v8 + jj] += as * (float)o[jj];
        }
    }

    float* dst = OUT + (size_t)bh * S * 64 + (size_t)(item * 128 + q) * 64 + 32 * half;
    #pragma unroll
    for (int v4 = 0; v4 < 8; ++v4) {
        float4 f = { acc[4*v4+0] * inv, acc[4*v4+1] * inv,
                     acc[4*v4+2] * inv, acc[4*v4+3] * inv };
        *(float4*)&dst[4 * v4] = f;
    }
}

extern "C" void kernel_launch(void* const* d_in, const int* in_sizes, int n_in,
                              void* d_out, int out_size, void* d_ws, size_t ws_size,
                              hipStream_t stream) {
    const float* q     = (const float*)d_in[0];
    const float* k     = (const float*)d_in[1];
    const float* v     = (const float*)d_in[2];
    const float* sinkw = (const float*)d_in[3];
    const int*   swin  = (const int*)d_in[4];
    float* out = (float*)d_out;

    const int H = in_sizes[3];                   // 16
    const int S = 2048;
    const int B = in_sizes[0] / (H * S * 64);    // 2
    const int NBH = B * H;                       // 32

    flex_r12_pre    <<<dim3(NBH * (S / 64)), 256, 0, stream>>>(k, v, d_ws, S);
    flex_r12_main   <<<dim3(NBH * 36),       NT,  0, stream>>>(q, sinkw, swin, d_ws, out, H, S);
    flex_r12_combine<<<dim3(NBH * 13),       256, 0, stream>>>(d_ws, out, H, S);
}